// Round 15
// baseline (123.859 us; speedup 1.0000x reference)
//
#include <hip/hip_runtime.h>
#include <hip/hip_bf16.h>
#include <cstdint>

#define NV 64000      // B*N nodes
#define DD 64         // hidden dim
#define FF 3          // input features
#define NE 1000000    // edges
#define BB 32         // batch (graphs)
#define SS 50         // timesteps
#define NN 2000       // nodes per graph
#define KB 1000       // coarse buckets (dst >> 6), 64 dsts each
#define CAP 1536      // records per bucket region (mean 1000, +17 sigma)
#define NBLKA 500     // partition blocks (round-15: 250->500 for 2x wave parallelism)
#define EPB (NE / NBLKA)  // 2000 edges per partition block
#define INVALID 0xFFFFFFFFu
#define RPW 16        // rows per wave in trans2pool (2000 % 16 == 0 -> graph-aligned)
#define NWAVES (NV / RPW)   // 4000
#define WPG (NN / RPW)      // 125 partials per graph
#define RST 20        // rT row stride (words): %4==0 keeps b128 alignment

// ---------------------------------------------------------------------------
// Fused setup: zero gcur + int64-vs-int32 detection.
// ---------------------------------------------------------------------------
__global__ __launch_bounds__(256) void setup_kernel(const int* __restrict__ ei,
                                                    int* __restrict__ flag,
                                                    int* __restrict__ gcur) {
    int i = blockIdx.x * 256 + threadIdx.x;
    if (i < KB) gcur[i] = 0;
    if (blockIdx.x == 0) {
        __shared__ int nz;
        if (threadIdx.x == 0) nz = 0;
        __syncthreads();
        int local = 0;
        for (int k = threadIdx.x; k < 4096; k += 256)
            local |= (ei[2 * k + 1] != 0);
        if (local) atomicOr(&nz, 1);
        __syncthreads();
        if (threadIdx.x == 0) *flag = (nz == 0) ? 1 : 0;
    }
}

// ---------------------------------------------------------------------------
// Partition edges into KB coarse bucket regions as packed 4B records
// (src<<6)|(dst&63). Single edge-list read; records staged in LDS.
// 500 blocks x 2000 edges: 16 KB LDS, ~2 blocks/CU (2x the waves of v1).
// ---------------------------------------------------------------------------
__global__ __launch_bounds__(256) void part_kernel(const int* __restrict__ ei32,
                                                   const int* __restrict__ flag,
                                                   int* __restrict__ gcur,
                                                   unsigned* __restrict__ parts) {
    __shared__ unsigned recs[EPB];   // 8 KB
    __shared__ int cnt[KB];          // 4 KB
    __shared__ int cur[KB];          // 4 KB
    const long long* ei64 = (const long long*)ei32;
    const int is64 = *flag;
    int t = threadIdx.x;
    int e0 = blockIdx.x * EPB;
    for (int i = t; i < KB; i += 256) cnt[i] = 0;
    __syncthreads();
    for (int i = t; i < EPB; i += 256) {
        int e = e0 + i;
        int s, d;
        if (is64) { s = (int)ei64[e]; d = (int)ei64[NE + e]; }
        else      { s = ei32[e];      d = ei32[NE + e]; }
        bool ok = (unsigned)s < NV && (unsigned)d < NV;
        recs[i] = ok ? (((unsigned)s << 16) | (unsigned)d) : INVALID;
        if (ok) atomicAdd(&cnt[d >> 6], 1);
    }
    __syncthreads();
    for (int b = t; b < KB; b += 256) {
        int c = cnt[b];
        cur[b] = (c > 0) ? atomicAdd(&gcur[b], c) : 0;
    }
    __syncthreads();
    for (int i = t; i < EPB; i += 256) {
        unsigned r = recs[i];
        if (r != INVALID) {
            int d = (int)(r & 0xFFFFu);
            int b = d >> 6;
            int pos = atomicAdd(&cur[b], 1);
            if (pos < CAP)
                parts[(size_t)b * CAP + pos] = ((r >> 16) << 6) | (unsigned)(d & 63);
        }
    }
}

// ---------------------------------------------------------------------------
// Per-bucket LDS counting sort -> beg/end + dinv; sorted src ids in place.
// ---------------------------------------------------------------------------
__global__ __launch_bounds__(256) void bsort_kernel(unsigned* __restrict__ parts,
                                                    const int* __restrict__ gcur,
                                                    int* __restrict__ beg,
                                                    int* __restrict__ end,
                                                    float* __restrict__ dinv) {
    __shared__ unsigned recs[CAP];
    __shared__ int srt[CAP];
    __shared__ int cnt64[64];
    __shared__ int pref[64];
    __shared__ int cur[64];
    int b = blockIdx.x, t = threadIdx.x;
    int cnt = min(gcur[b], CAP);
    unsigned* p = parts + (size_t)b * CAP;
    if (t < 64) cnt64[t] = 0;
    __syncthreads();
    for (int i = t; i < cnt; i += 256) {
        unsigned r = p[i];
        recs[i] = r;
        atomicAdd(&cnt64[r & 63u], 1);
    }
    __syncthreads();
    if (t < 64) pref[t] = cnt64[t];
    __syncthreads();
    #pragma unroll
    for (int off = 1; off < 64; off <<= 1) {
        int v = (t < 64 && t >= off) ? pref[t - off] : 0;
        __syncthreads();
        if (t < 64) pref[t] += v;
        __syncthreads();
    }
    if (t < 64) {
        int ex = pref[t] - cnt64[t];
        cur[t] = ex;
        int node = (b << 6) + t;
        beg[node] = b * CAP + ex;
        end[node] = b * CAP + ex + cnt64[t];
        dinv[node] = rsqrtf((float)(cnt64[t] + 1));
    }
    __syncthreads();
    for (int i = t; i < cnt; i += 256) {
        unsigned r = recs[i];
        int pos = atomicAdd(&cur[r & 63u], 1);
        srt[pos] = (int)(r >> 6);
    }
    __syncthreads();
    for (int i = t; i < cnt; i += 256) p[i] = (unsigned)srt[i];
}

// p0[node*3+f] = dinv[node] * mean over S of x[b][s][n][f]
__global__ void tmean_kernel(const float* __restrict__ x, const float* __restrict__ dinv,
                             float* __restrict__ p0) {
    int tid = blockIdx.x * blockDim.x + threadIdx.x;
    if (tid >= NV * FF) return;
    int nf = tid % (NN * FF);
    int b  = tid / (NN * FF);
    const float* xp = x + (size_t)b * SS * NN * FF + nf;
    float acc = 0.f;
    #pragma unroll
    for (int s = 0; s < SS; ++s) acc += xp[(size_t)s * NN * FF];
    int node = tid / 3;
    p0[tid] = dinv[node] * acc * (1.0f / SS);
}

// 3-dim aggregation: q04 = {sum p0[src] + p0[dst], dinv}. p0 L2-resident.
__global__ __launch_bounds__(256) void agg3_kernel(const int* __restrict__ beg,
                                                   const int* __restrict__ end,
                                                   const unsigned* __restrict__ srcs,
                                                   const float* __restrict__ p0,
                                                   const float* __restrict__ dinv,
                                                   float4* __restrict__ q04) {
    int node = blockIdx.x * 256 + threadIdx.x;
    if (node >= NV) return;
    int e = beg[node], en = end[node];
    float a0 = p0[node * 3 + 0], a1 = p0[node * 3 + 1], a2 = p0[node * 3 + 2];
    for (; e + 2 <= en; e += 2) {
        int s0 = srcs[e] * 3, s1 = srcs[e + 1] * 3;
        float u0 = p0[s0], u1 = p0[s0 + 1], u2 = p0[s0 + 2];
        float w0 = p0[s1], w1 = p0[s1 + 1], w2 = p0[s1 + 2];
        a0 += u0 + w0; a1 += u1 + w1; a2 += u2 + w2;
    }
    for (; e < en; ++e) {
        int s = srcs[e] * 3;
        a0 += p0[s]; a1 += p0[s + 1]; a2 += p0[s + 2];
    }
    q04[node] = make_float4(a0, a1, a2, dinv[node]);
}

// p1 = dinv * relu(dinv*(q0@W1) + b1)
__global__ void trans1_kernel(const float4* __restrict__ q04,
                              const float* __restrict__ W1, const float* __restrict__ b1,
                              float* __restrict__ p1) {
    int tid = blockIdx.x * blockDim.x + threadIdx.x;  // NV*DD
    if (tid >= NV * DD) return;
    int node = tid >> 6, d = tid & 63;
    float4 q = q04[node];
    float h = fmaf(q.w, fmaf(q.x, W1[d], fmaf(q.y, W1[64 + d], q.z * W1[128 + d])), b1[d]);
    p1[tid] = q.w * fmaxf(h, 0.f);
}

// ---------------------------------------------------------------------------
// 64-dim aggregation v3: float4-per-lane + 4-deep gather batching.
// One wave per dst node; 16-lane group grp handles edges e0+grp+4k.
// Round-14 post-mortem: ~2.7 TB/s effective fill rate = outstanding-miss
// limited, so issue FOUR independent dwordx4 gathers per lane before any
// accumulation (2x the in-flight misses of v2).
// ---------------------------------------------------------------------------
__global__ __launch_bounds__(256) void agg64_kernel(const int* __restrict__ beg,
                                                    const int* __restrict__ end,
                                                    const unsigned* __restrict__ srcs,
                                                    const float* __restrict__ g,
                                                    float* __restrict__ raw) {
    int lane = threadIdx.x & 63;
    int node = (blockIdx.x * blockDim.x + threadIdx.x) >> 6;
    if (node >= NV) return;
    int grp = lane >> 4, sub = lane & 15;
    int e0 = beg[node], en = end[node];
    float4 acc;
    if (grp == 0) {
        acc = ((const float4*)(g + ((size_t)node << 6)))[sub];  // self loop
    } else {
        acc = make_float4(0.f, 0.f, 0.f, 0.f);
    }
    int e = e0 + grp;
    for (; e + 12 < en; e += 16) {
        int s0 = srcs[e], s1 = srcs[e + 4], s2 = srcs[e + 8], s3 = srcs[e + 12];
        float4 v0 = ((const float4*)(g + ((size_t)s0 << 6)))[sub];
        float4 v1 = ((const float4*)(g + ((size_t)s1 << 6)))[sub];
        float4 v2 = ((const float4*)(g + ((size_t)s2 << 6)))[sub];
        float4 v3 = ((const float4*)(g + ((size_t)s3 << 6)))[sub];
        acc.x += (v0.x + v1.x) + (v2.x + v3.x);
        acc.y += (v0.y + v1.y) + (v2.y + v3.y);
        acc.z += (v0.z + v1.z) + (v2.z + v3.z);
        acc.w += (v0.w + v1.w) + (v2.w + v3.w);
    }
    for (; e < en; e += 4) {
        int s = srcs[e];
        float4 v = ((const float4*)(g + ((size_t)s << 6)))[sub];
        acc.x += v.x; acc.y += v.y; acc.z += v.z; acc.w += v.w;
    }
    acc.x += __shfl_xor(acc.x, 16); acc.y += __shfl_xor(acc.y, 16);
    acc.z += __shfl_xor(acc.z, 16); acc.w += __shfl_xor(acc.w, 16);
    acc.x += __shfl_xor(acc.x, 32); acc.y += __shfl_xor(acc.y, 32);
    acc.z += __shfl_xor(acc.z, 32); acc.w += __shfl_xor(acc.w, 32);
    if (grp == 0)
        ((float4*)(raw + ((size_t)node << 6)))[sub] = acc;
}

// ---------------------------------------------------------------------------
// Fused layer-2 transform + partial pooling: 4x4 register-tiled GEMM.
// Per k: ONE ds_read_b128 of W2[k][c0..c0+4) + ONE ds_read_b128 of the
// transposed row tile feed SIXTEEN FMAs (0.125 fetch/FMA). ~50 VGPR.
// ---------------------------------------------------------------------------
__global__ __launch_bounds__(256) void trans2pool_kernel(const float* __restrict__ q1,
                                                         const float* __restrict__ dinv,
                                                         const float* __restrict__ b2,
                                                         const float* __restrict__ W2,
                                                         float* __restrict__ partials) {
    __shared__ float w2s[64 * 64];        // 16 KB, [k][d]
    __shared__ float rT[4][64 * RST];     // 20 KB, per-wave transposed rows [k][r]
    int t = threadIdx.x;
    int lane = t & 63, wvid = t >> 6;
    for (int i = t; i < 64 * 64; i += 256) w2s[i] = W2[i];

    int wid = blockIdx.x * 4 + wvid;
    int n0 = wid * RPW;
    float v[16];
    #pragma unroll
    for (int i = 0; i < 16; ++i) v[i] = q1[((size_t)(n0 + i) << 6) + lane];
    float* rw = rT[wvid];
    #pragma unroll
    for (int r0 = 0; r0 < 16; r0 += 4)
        *(float4*)&rw[lane * RST + r0] = make_float4(v[r0], v[r0 + 1], v[r0 + 2], v[r0 + 3]);
    __syncthreads();

    int ri0 = (lane >> 4) * 4;            // row sub-tile: 0,4,8,12
    int c0 = (lane & 15) * 4;             // col sub-tile: 0..60
    float acc00 = 0.f, acc01 = 0.f, acc02 = 0.f, acc03 = 0.f;
    float acc10 = 0.f, acc11 = 0.f, acc12 = 0.f, acc13 = 0.f;
    float acc20 = 0.f, acc21 = 0.f, acc22 = 0.f, acc23 = 0.f;
    float acc30 = 0.f, acc31 = 0.f, acc32 = 0.f, acc33 = 0.f;
    #pragma unroll 2
    for (int k = 0; k < 64; ++k) {
        float4 w4 = *(const float4*)&w2s[k * 64 + c0];
        float4 r4 = *(const float4*)&rw[k * RST + ri0];
        acc00 = fmaf(r4.x, w4.x, acc00); acc01 = fmaf(r4.x, w4.y, acc01);
        acc02 = fmaf(r4.x, w4.z, acc02); acc03 = fmaf(r4.x, w4.w, acc03);
        acc10 = fmaf(r4.y, w4.x, acc10); acc11 = fmaf(r4.y, w4.y, acc11);
        acc12 = fmaf(r4.y, w4.z, acc12); acc13 = fmaf(r4.y, w4.w, acc13);
        acc20 = fmaf(r4.z, w4.x, acc20); acc21 = fmaf(r4.z, w4.y, acc21);
        acc22 = fmaf(r4.z, w4.z, acc22); acc23 = fmaf(r4.z, w4.w, acc23);
        acc30 = fmaf(r4.w, w4.x, acc30); acc31 = fmaf(r4.w, w4.y, acc31);
        acc32 = fmaf(r4.w, w4.z, acc32); acc33 = fmaf(r4.w, w4.w, acc33);
    }
    float4 bv = *(const float4*)&b2[c0];
    float d0 = dinv[n0 + ri0 + 0], d1 = dinv[n0 + ri0 + 1];
    float d2 = dinv[n0 + ri0 + 2], d3 = dinv[n0 + ri0 + 3];
    float s0 = fmaxf(fmaf(d0, acc00, bv.x), 0.f) + fmaxf(fmaf(d1, acc10, bv.x), 0.f)
             + fmaxf(fmaf(d2, acc20, bv.x), 0.f) + fmaxf(fmaf(d3, acc30, bv.x), 0.f);
    float s1 = fmaxf(fmaf(d0, acc01, bv.y), 0.f) + fmaxf(fmaf(d1, acc11, bv.y), 0.f)
             + fmaxf(fmaf(d2, acc21, bv.y), 0.f) + fmaxf(fmaf(d3, acc31, bv.y), 0.f);
    float s2 = fmaxf(fmaf(d0, acc02, bv.z), 0.f) + fmaxf(fmaf(d1, acc12, bv.z), 0.f)
             + fmaxf(fmaf(d2, acc22, bv.z), 0.f) + fmaxf(fmaf(d3, acc32, bv.z), 0.f);
    float s3 = fmaxf(fmaf(d0, acc03, bv.w), 0.f) + fmaxf(fmaf(d1, acc13, bv.w), 0.f)
             + fmaxf(fmaf(d2, acc23, bv.w), 0.f) + fmaxf(fmaf(d3, acc33, bv.w), 0.f);
    s0 += __shfl_xor(s0, 16); s1 += __shfl_xor(s1, 16);
    s2 += __shfl_xor(s2, 16); s3 += __shfl_xor(s3, 16);
    s0 += __shfl_xor(s0, 32); s1 += __shfl_xor(s1, 32);
    s2 += __shfl_xor(s2, 32); s3 += __shfl_xor(s3, 32);
    if (lane < 16)
        *(float4*)&partials[(size_t)wid * 64 + c0] = make_float4(s0, s1, s2, s3);
}

// Reduce WPG=125 partials per graph; apply head.
__global__ __launch_bounds__(64) void pool_finish_kernel(const float* __restrict__ partials,
                                                         const float* __restrict__ Wh,
                                                         const float* __restrict__ bh,
                                                         float* __restrict__ out) {
    __shared__ float pooled[64];
    int b = blockIdx.x;
    int t = threadIdx.x;
    float s = 0.f;
    for (int c = 0; c < WPG; ++c)
        s += partials[((size_t)(b * WPG + c)) * 64 + t];
    pooled[t] = s * (1.0f / NN);
    __syncthreads();
    if (t < 2) {
        float o = bh[t];
        #pragma unroll 16
        for (int k = 0; k < 64; ++k) o += pooled[k] * Wh[k * 2 + t];
        out[b * 2 + t] = o;
    }
}

extern "C" void kernel_launch(void* const* d_in, const int* in_sizes, int n_in,
                              void* d_out, int out_size, void* d_ws, size_t ws_size,
                              hipStream_t stream) {
    const float* x  = (const float*)d_in[0];
    const int*   ei = (const int*)d_in[1];
    const float* W1 = (const float*)d_in[2];
    const float* b1 = (const float*)d_in[3];
    const float* W2 = (const float*)d_in[4];
    const float* b2 = (const float*)d_in[5];
    const float* Wh = (const float*)d_in[6];
    const float* bh = (const float*)d_in[7];
    float* out = (float*)d_out;

    float* ws   = (float*)d_ws;
    float* bufA = ws;                          // NV*DD  (p1)
    float* bufB = bufA + (size_t)NV * DD;      // NV*DD  (q1)
    float* p0   = bufB + (size_t)NV * DD;      // NV*FF
    float4* q04 = (float4*)(p0 + (size_t)NV * FF);  // NV
    float* dinv = (float*)(q04 + NV);          // NV
    float* partials = dinv + NV;               // NWAVES*64
    unsigned* parts = (unsigned*)(partials + (size_t)NWAVES * 64);  // KB*CAP
    int*   beg  = (int*)(parts + (size_t)KB * CAP);                 // NV
    int*   end  = beg + NV;                    // NV
    int*   gcur = end + NV;                    // KB
    int*   flag = gcur + KB;                   // 1

    // --- Build bucketed, per-bucket-sorted edge structure ---
    setup_kernel<<<4, 256, 0, stream>>>(ei, flag, gcur);
    part_kernel<<<NBLKA, 256, 0, stream>>>(ei, flag, gcur, parts);
    bsort_kernel<<<KB, 256, 0, stream>>>(parts, gcur, beg, end, dinv);

    // --- p0 = dinv * temporal-mean(x) ---
    tmean_kernel<<<(NV * FF + 255) / 256, 256, 0, stream>>>(x, dinv, p0);

    // --- Layer 1 aggregation (3-dim gather) -> q04 = {q0, dinv} ---
    agg3_kernel<<<(NV + 255) / 256, 256, 0, stream>>>(beg, end, parts, p0, dinv, q04);

    // --- Layer 1 transform (once per node) ---
    trans1_kernel<<<NV * DD / 256, 256, 0, stream>>>(q04, W1, b1, bufA);

    // --- Layer 2 aggregation (4-deep batched float4 gathers) ---
    agg64_kernel<<<NV * 64 / 256, 256, 0, stream>>>(beg, end, parts, bufA, bufB);

    // --- Fused layer-2 transform + partial pool (4x4 register-tiled GEMM) ---
    trans2pool_kernel<<<NWAVES / 4, 256, 0, stream>>>(bufB, dinv, b2, W2, partials);

    // --- Head ---
    pool_finish_kernel<<<BB, 64, 0, stream>>>(partials, Wh, bh, out);
}

// Round 16
// 121.419 us; speedup vs baseline: 1.0201x; 1.0201x over previous
//
#include <hip/hip_runtime.h>
#include <hip/hip_bf16.h>
#include <cstdint>

#define NV 64000      // B*N nodes
#define DD 64         // hidden dim
#define FF 3          // input features
#define NE 1000000    // edges
#define BB 32         // batch (graphs)
#define SS 50         // timesteps
#define NN 2000       // nodes per graph
#define KB 1000       // coarse buckets (dst >> 6), 64 dsts each
#define CAP 1536      // records per bucket region (mean 1000, +17 sigma)
#define NBLKA 250     // partition blocks (round-16: reverted to 250; 500 regressed)
#define EPB (NE / NBLKA)  // 4000 edges per partition block
#define INVALID 0xFFFFFFFFu
#define NTILES (NV / 16)    // 4000 blocks of 16 nodes for aggtrans
#define WPG (NN / 16)       // 125 partials per graph
#define RST 20        // rT row stride (words): %4==0 keeps b128 alignment

// ---------------------------------------------------------------------------
// Fused setup: zero gcur + int64-vs-int32 detection.
// ---------------------------------------------------------------------------
__global__ __launch_bounds__(256) void setup_kernel(const int* __restrict__ ei,
                                                    int* __restrict__ flag,
                                                    int* __restrict__ gcur) {
    int i = blockIdx.x * 256 + threadIdx.x;
    if (i < KB) gcur[i] = 0;
    if (blockIdx.x == 0) {
        __shared__ int nz;
        if (threadIdx.x == 0) nz = 0;
        __syncthreads();
        int local = 0;
        for (int k = threadIdx.x; k < 4096; k += 256)
            local |= (ei[2 * k + 1] != 0);
        if (local) atomicOr(&nz, 1);
        __syncthreads();
        if (threadIdx.x == 0) *flag = (nz == 0) ? 1 : 0;
    }
}

// ---------------------------------------------------------------------------
// Partition edges into KB coarse bucket regions as packed 4B records
// (src<<6)|(dst&63). Single edge-list read; records staged in LDS.
// ---------------------------------------------------------------------------
__global__ __launch_bounds__(256) void part_kernel(const int* __restrict__ ei32,
                                                   const int* __restrict__ flag,
                                                   int* __restrict__ gcur,
                                                   unsigned* __restrict__ parts) {
    __shared__ unsigned recs[EPB];   // 16 KB
    __shared__ int cnt[KB];          // 4 KB
    __shared__ int cur[KB];          // 4 KB
    const long long* ei64 = (const long long*)ei32;
    const int is64 = *flag;
    int t = threadIdx.x;
    int e0 = blockIdx.x * EPB;
    for (int i = t; i < KB; i += 256) cnt[i] = 0;
    __syncthreads();
    for (int i = t; i < EPB; i += 256) {
        int e = e0 + i;
        int s, d;
        if (is64) { s = (int)ei64[e]; d = (int)ei64[NE + e]; }
        else      { s = ei32[e];      d = ei32[NE + e]; }
        bool ok = (unsigned)s < NV && (unsigned)d < NV;
        recs[i] = ok ? (((unsigned)s << 16) | (unsigned)d) : INVALID;
        if (ok) atomicAdd(&cnt[d >> 6], 1);
    }
    __syncthreads();
    for (int b = t; b < KB; b += 256) {
        int c = cnt[b];
        cur[b] = (c > 0) ? atomicAdd(&gcur[b], c) : 0;
    }
    __syncthreads();
    for (int i = t; i < EPB; i += 256) {
        unsigned r = recs[i];
        if (r != INVALID) {
            int d = (int)(r & 0xFFFFu);
            int b = d >> 6;
            int pos = atomicAdd(&cur[b], 1);
            if (pos < CAP)
                parts[(size_t)b * CAP + pos] = ((r >> 16) << 6) | (unsigned)(d & 63);
        }
    }
}

// ---------------------------------------------------------------------------
// Per-bucket LDS counting sort -> beg/end + dinv; sorted src ids in place.
// ---------------------------------------------------------------------------
__global__ __launch_bounds__(256) void bsort_kernel(unsigned* __restrict__ parts,
                                                    const int* __restrict__ gcur,
                                                    int* __restrict__ beg,
                                                    int* __restrict__ end,
                                                    float* __restrict__ dinv) {
    __shared__ unsigned recs[CAP];
    __shared__ int srt[CAP];
    __shared__ int cnt64[64];
    __shared__ int pref[64];
    __shared__ int cur[64];
    int b = blockIdx.x, t = threadIdx.x;
    int cnt = min(gcur[b], CAP);
    unsigned* p = parts + (size_t)b * CAP;
    if (t < 64) cnt64[t] = 0;
    __syncthreads();
    for (int i = t; i < cnt; i += 256) {
        unsigned r = p[i];
        recs[i] = r;
        atomicAdd(&cnt64[r & 63u], 1);
    }
    __syncthreads();
    if (t < 64) pref[t] = cnt64[t];
    __syncthreads();
    #pragma unroll
    for (int off = 1; off < 64; off <<= 1) {
        int v = (t < 64 && t >= off) ? pref[t - off] : 0;
        __syncthreads();
        if (t < 64) pref[t] += v;
        __syncthreads();
    }
    if (t < 64) {
        int ex = pref[t] - cnt64[t];
        cur[t] = ex;
        int node = (b << 6) + t;
        beg[node] = b * CAP + ex;
        end[node] = b * CAP + ex + cnt64[t];
        dinv[node] = rsqrtf((float)(cnt64[t] + 1));
    }
    __syncthreads();
    for (int i = t; i < cnt; i += 256) {
        unsigned r = recs[i];
        int pos = atomicAdd(&cur[r & 63u], 1);
        srt[pos] = (int)(r >> 6);
    }
    __syncthreads();
    for (int i = t; i < cnt; i += 256) p[i] = (unsigned)srt[i];
}

// p0[node*3+f] = dinv[node] * mean over S of x[b][s][n][f]
__global__ void tmean_kernel(const float* __restrict__ x, const float* __restrict__ dinv,
                             float* __restrict__ p0) {
    int tid = blockIdx.x * blockDim.x + threadIdx.x;
    if (tid >= NV * FF) return;
    int nf = tid % (NN * FF);
    int b  = tid / (NN * FF);
    const float* xp = x + (size_t)b * SS * NN * FF + nf;
    float acc = 0.f;
    #pragma unroll
    for (int s = 0; s < SS; ++s) acc += xp[(size_t)s * NN * FF];
    int node = tid / 3;
    p0[tid] = dinv[node] * acc * (1.0f / SS);
}

// 3-dim aggregation: q04 = {sum p0[src] + p0[dst], dinv}. p0 L2-resident.
__global__ __launch_bounds__(256) void agg3_kernel(const int* __restrict__ beg,
                                                   const int* __restrict__ end,
                                                   const unsigned* __restrict__ srcs,
                                                   const float* __restrict__ p0,
                                                   const float* __restrict__ dinv,
                                                   float4* __restrict__ q04) {
    int node = blockIdx.x * 256 + threadIdx.x;
    if (node >= NV) return;
    int e = beg[node], en = end[node];
    float a0 = p0[node * 3 + 0], a1 = p0[node * 3 + 1], a2 = p0[node * 3 + 2];
    for (; e + 2 <= en; e += 2) {
        int s0 = srcs[e] * 3, s1 = srcs[e + 1] * 3;
        float u0 = p0[s0], u1 = p0[s0 + 1], u2 = p0[s0 + 2];
        float w0 = p0[s1], w1 = p0[s1 + 1], w2 = p0[s1 + 2];
        a0 += u0 + w0; a1 += u1 + w1; a2 += u2 + w2;
    }
    for (; e < en; ++e) {
        int s = srcs[e] * 3;
        a0 += p0[s]; a1 += p0[s + 1]; a2 += p0[s + 2];
    }
    q04[node] = make_float4(a0, a1, a2, dinv[node]);
}

// p1 = dinv * relu(dinv*(q0@W1) + b1)
__global__ void trans1_kernel(const float4* __restrict__ q04,
                              const float* __restrict__ W1, const float* __restrict__ b1,
                              float* __restrict__ p1) {
    int tid = blockIdx.x * blockDim.x + threadIdx.x;  // NV*DD
    if (tid >= NV * DD) return;
    int node = tid >> 6, d = tid & 63;
    float4 q = q04[node];
    float h = fmaf(q.w, fmaf(q.x, W1[d], fmaf(q.y, W1[64 + d], q.z * W1[128 + d])), b1[d]);
    p1[tid] = q.w * fmaxf(h, 0.f);
}

// ---------------------------------------------------------------------------
// FUSED layer-2 aggregation + transform + partial pool. Block = 16 dst nodes,
// 4 waves. Aggregation: 16-lane group owns ONE node's full contiguous edge
// range (~15.6 sequential gathers, 2-deep unrolled; lane sub covers 16B of
// the 256B row). Result written DIRECTLY to LDS transposed (rT[k][r]) -- the
// layout the GEMM needs, so the q1 global round-trip (32 MB) disappears.
// After one barrier: per k, one broadcast ds_read_b128 (4-row quad) + one
// conflict-free ds_read_b32 (W2 col) feed 4 FMAs/lane; relu+dinv+b2 epilogue;
// shfl reduce over row-quads -> one 64-dim partial per block.
// LDS = 16K (w2s) + 5K (rT) = 21.5 KB -> 7 blocks/CU = 28 waves/CU.
// ---------------------------------------------------------------------------
__global__ __launch_bounds__(256) void aggtrans_kernel(const int* __restrict__ beg,
                                                       const int* __restrict__ end,
                                                       const unsigned* __restrict__ srcs,
                                                       const float* __restrict__ g,
                                                       const float* __restrict__ dinv,
                                                       const float* __restrict__ b2,
                                                       const float* __restrict__ W2,
                                                       float* __restrict__ partials) {
    __shared__ float w2s[64 * 64];   // 16 KB, [k][d]
    __shared__ float rT[64 * RST];   // 5 KB, transposed 16-row tile [k][r]
    int t = threadIdx.x;
    int lane = t & 63, w = t >> 6;
    for (int i = t; i < 64 * 64; i += 256) w2s[i] = W2[i];

    int gidx = lane >> 4, sub = lane & 15;
    int n0 = blockIdx.x * 16;
    int r = 4 * w + gidx;            // row 0..15 within tile
    int n = n0 + r;
    float4 acc = ((const float4*)(g + ((size_t)n << 6)))[sub];  // self loop
    int e = beg[n], en = end[n];
    for (; e + 1 < en; e += 2) {
        int s0 = srcs[e], s1 = srcs[e + 1];
        float4 v0 = ((const float4*)(g + ((size_t)s0 << 6)))[sub];
        float4 v1 = ((const float4*)(g + ((size_t)s1 << 6)))[sub];
        acc.x += v0.x + v1.x; acc.y += v0.y + v1.y;
        acc.z += v0.z + v1.z; acc.w += v0.w + v1.w;
    }
    if (e < en) {
        float4 v = ((const float4*)(g + ((size_t)srcs[e] << 6)))[sub];
        acc.x += v.x; acc.y += v.y; acc.z += v.z; acc.w += v.w;
    }
    // transposed store: row r, dims 4*sub..4*sub+3
    rT[(4 * sub + 0) * RST + r] = acc.x;
    rT[(4 * sub + 1) * RST + r] = acc.y;
    rT[(4 * sub + 2) * RST + r] = acc.z;
    rT[(4 * sub + 3) * RST + r] = acc.w;
    __syncthreads();

    // GEMM: lane -> row quad ri0 = gidx*4, col c = w*16 + sub
    int ri0 = gidx * 4;
    int c = w * 16 + sub;
    float a0 = 0.f, a1 = 0.f, a2 = 0.f, a3 = 0.f;
    #pragma unroll 4
    for (int k = 0; k < 64; ++k) {
        float4 r4 = *(const float4*)&rT[k * RST + ri0];
        float wv = w2s[k * 64 + c];
        a0 = fmaf(r4.x, wv, a0);
        a1 = fmaf(r4.y, wv, a1);
        a2 = fmaf(r4.z, wv, a2);
        a3 = fmaf(r4.w, wv, a3);
    }
    float bb = b2[c];
    float d0 = dinv[n0 + ri0 + 0], d1 = dinv[n0 + ri0 + 1];
    float d2 = dinv[n0 + ri0 + 2], d3 = dinv[n0 + ri0 + 3];
    float s = fmaxf(fmaf(d0, a0, bb), 0.f) + fmaxf(fmaf(d1, a1, bb), 0.f)
            + fmaxf(fmaf(d2, a2, bb), 0.f) + fmaxf(fmaf(d3, a3, bb), 0.f);
    s += __shfl_xor(s, 16);
    s += __shfl_xor(s, 32);
    if (gidx == 0)
        partials[(size_t)blockIdx.x * 64 + c] = s;
}

// Reduce WPG=125 partials per graph; apply head.
__global__ __launch_bounds__(64) void pool_finish_kernel(const float* __restrict__ partials,
                                                         const float* __restrict__ Wh,
                                                         const float* __restrict__ bh,
                                                         float* __restrict__ out) {
    __shared__ float pooled[64];
    int b = blockIdx.x;
    int t = threadIdx.x;
    float s = 0.f;
    for (int c = 0; c < WPG; ++c)
        s += partials[((size_t)(b * WPG + c)) * 64 + t];
    pooled[t] = s * (1.0f / NN);
    __syncthreads();
    if (t < 2) {
        float o = bh[t];
        #pragma unroll 16
        for (int k = 0; k < 64; ++k) o += pooled[k] * Wh[k * 2 + t];
        out[b * 2 + t] = o;
    }
}

extern "C" void kernel_launch(void* const* d_in, const int* in_sizes, int n_in,
                              void* d_out, int out_size, void* d_ws, size_t ws_size,
                              hipStream_t stream) {
    const float* x  = (const float*)d_in[0];
    const int*   ei = (const int*)d_in[1];
    const float* W1 = (const float*)d_in[2];
    const float* b1 = (const float*)d_in[3];
    const float* W2 = (const float*)d_in[4];
    const float* b2 = (const float*)d_in[5];
    const float* Wh = (const float*)d_in[6];
    const float* bh = (const float*)d_in[7];
    float* out = (float*)d_out;

    float* ws   = (float*)d_ws;
    float* bufA = ws;                          // NV*DD  (p1)
    float* bufB = bufA + (size_t)NV * DD;      // NV*DD  (unused, kept for layout)
    float* p0   = bufB + (size_t)NV * DD;      // NV*FF
    float4* q04 = (float4*)(p0 + (size_t)NV * FF);  // NV
    float* dinv = (float*)(q04 + NV);          // NV
    float* partials = dinv + NV;               // NTILES*64
    unsigned* parts = (unsigned*)(partials + (size_t)NTILES * 64);  // KB*CAP
    int*   beg  = (int*)(parts + (size_t)KB * CAP);                 // NV
    int*   end  = beg + NV;                    // NV
    int*   gcur = end + NV;                    // KB
    int*   flag = gcur + KB;                   // 1

    // --- Build bucketed, per-bucket-sorted edge structure ---
    setup_kernel<<<4, 256, 0, stream>>>(ei, flag, gcur);
    part_kernel<<<NBLKA, 256, 0, stream>>>(ei, flag, gcur, parts);
    bsort_kernel<<<KB, 256, 0, stream>>>(parts, gcur, beg, end, dinv);

    // --- p0 = dinv * temporal-mean(x) ---
    tmean_kernel<<<(NV * FF + 255) / 256, 256, 0, stream>>>(x, dinv, p0);

    // --- Layer 1 aggregation (3-dim gather) -> q04 = {q0, dinv} ---
    agg3_kernel<<<(NV + 255) / 256, 256, 0, stream>>>(beg, end, parts, p0, dinv, q04);

    // --- Layer 1 transform (once per node) ---
    trans1_kernel<<<NV * DD / 256, 256, 0, stream>>>(q04, W1, b1, bufA);

    // --- FUSED layer-2 aggregation + transform + partial pool ---
    aggtrans_kernel<<<NTILES, 256, 0, stream>>>(beg, end, parts, bufA, dinv, b2, W2, partials);

    // --- Head ---
    pool_finish_kernel<<<BB, 64, 0, stream>>>(partials, Wh, bh, out);
}

// Round 17
// 114.664 us; speedup vs baseline: 1.0802x; 1.0589x over previous
//
#include <hip/hip_runtime.h>
#include <hip/hip_bf16.h>
#include <cstdint>

#define NV 64000      // B*N nodes
#define DD 64         // hidden dim
#define FF 3          // input features
#define NE 1000000    // edges
#define BB 32         // batch (graphs)
#define SS 50         // timesteps
#define NN 2000       // nodes per graph
#define KB 1000       // coarse buckets (dst >> 6), 64 dsts each
#define CAP 1536      // records per bucket region (mean 1000, +17 sigma)
#define NBLKA 250     // partition blocks
#define EPB (NE / NBLKA)  // 4000 edges per partition block
#define TMB 750       // tmean blocks (750*256 == NV*FF)
#define INVALID 0xFFFFFFFFu
#define RPW 16        // rows per wave in trans2pool
#define NWAVES (NV / RPW)   // 4000
#define WPG (NN / RPW)      // 125 partials per graph
#define RST 20        // rT row stride (words): %4==0 keeps b128 alignment

// ---------------------------------------------------------------------------
// Fused setup: zero gcur + int64-vs-int32 detection.
// ---------------------------------------------------------------------------
__global__ __launch_bounds__(256) void setup_kernel(const int* __restrict__ ei,
                                                    int* __restrict__ flag,
                                                    int* __restrict__ gcur) {
    int i = blockIdx.x * 256 + threadIdx.x;
    if (i < KB) gcur[i] = 0;
    if (blockIdx.x == 0) {
        __shared__ int nz;
        if (threadIdx.x == 0) nz = 0;
        __syncthreads();
        int local = 0;
        for (int k = threadIdx.x; k < 4096; k += 256)
            local |= (ei[2 * k + 1] != 0);
        if (local) atomicOr(&nz, 1);
        __syncthreads();
        if (threadIdx.x == 0) *flag = (nz == 0) ? 1 : 0;
    }
}

// ---------------------------------------------------------------------------
// FAT kernel: blocks [0,NBLKA) partition edges into buckets (latency/atomic
// bound, <16% HBM); blocks [NBLKA,NBLKA+TMB) stream the temporal mean
// (HBM-bound) -> overlap hides tmean entirely. tmean writes the RAW mean;
// dinv scaling is applied in bsort's tail (dinv doesn't exist yet here).
// ---------------------------------------------------------------------------
__global__ __launch_bounds__(256) void part_tmean_kernel(const int* __restrict__ ei32,
                                                         const int* __restrict__ flag,
                                                         int* __restrict__ gcur,
                                                         unsigned* __restrict__ parts,
                                                         const float* __restrict__ x,
                                                         float* __restrict__ p0) {
    __shared__ unsigned recs[EPB];   // 16 KB
    __shared__ int cnt[KB];          // 4 KB
    __shared__ int cur[KB];          // 4 KB
    int t = threadIdx.x;
    if (blockIdx.x >= NBLKA) {
        // --- tmean branch: raw mean over S ---
        int tid = (blockIdx.x - NBLKA) * 256 + t;   // < NV*FF
        int nf = tid % (NN * FF);
        int b  = tid / (NN * FF);
        const float* xp = x + (size_t)b * SS * NN * FF + nf;
        float acc = 0.f;
        #pragma unroll
        for (int s = 0; s < SS; ++s) acc += xp[(size_t)s * NN * FF];
        p0[tid] = acc * (1.0f / SS);
        return;
    }
    // --- part branch ---
    const long long* ei64 = (const long long*)ei32;
    const int is64 = *flag;
    int e0 = blockIdx.x * EPB;
    for (int i = t; i < KB; i += 256) cnt[i] = 0;
    __syncthreads();
    for (int i = t; i < EPB; i += 256) {
        int e = e0 + i;
        int s, d;
        if (is64) { s = (int)ei64[e]; d = (int)ei64[NE + e]; }
        else      { s = ei32[e];      d = ei32[NE + e]; }
        bool ok = (unsigned)s < NV && (unsigned)d < NV;
        recs[i] = ok ? (((unsigned)s << 16) | (unsigned)d) : INVALID;
        if (ok) atomicAdd(&cnt[d >> 6], 1);
    }
    __syncthreads();
    for (int b = t; b < KB; b += 256) {
        int c = cnt[b];
        cur[b] = (c > 0) ? atomicAdd(&gcur[b], c) : 0;
    }
    __syncthreads();
    for (int i = t; i < EPB; i += 256) {
        unsigned r = recs[i];
        if (r != INVALID) {
            int d = (int)(r & 0xFFFFu);
            int b = d >> 6;
            int pos = atomicAdd(&cur[b], 1);
            if (pos < CAP)
                parts[(size_t)b * CAP + pos] = ((r >> 16) << 6) | (unsigned)(d & 63);
        }
    }
}

// ---------------------------------------------------------------------------
// Per-bucket LDS counting sort -> beg/end + dinv; sorted src ids in place.
// Tail: scale this bucket's 64 p0 rows (192 floats) by dinv (cnt64 in LDS).
// ---------------------------------------------------------------------------
__global__ __launch_bounds__(256) void bsort_kernel(unsigned* __restrict__ parts,
                                                    const int* __restrict__ gcur,
                                                    int* __restrict__ beg,
                                                    int* __restrict__ end,
                                                    float* __restrict__ dinv,
                                                    float* __restrict__ p0) {
    __shared__ unsigned recs[CAP];
    __shared__ int srt[CAP];
    __shared__ int cnt64[64];
    __shared__ int pref[64];
    __shared__ int cur[64];
    int b = blockIdx.x, t = threadIdx.x;
    int cnt = min(gcur[b], CAP);
    unsigned* p = parts + (size_t)b * CAP;
    if (t < 64) cnt64[t] = 0;
    __syncthreads();
    for (int i = t; i < cnt; i += 256) {
        unsigned r = p[i];
        recs[i] = r;
        atomicAdd(&cnt64[r & 63u], 1);
    }
    __syncthreads();
    if (t < 64) pref[t] = cnt64[t];
    __syncthreads();
    #pragma unroll
    for (int off = 1; off < 64; off <<= 1) {
        int v = (t < 64 && t >= off) ? pref[t - off] : 0;
        __syncthreads();
        if (t < 64) pref[t] += v;
        __syncthreads();
    }
    if (t < 64) {
        int ex = pref[t] - cnt64[t];
        cur[t] = ex;
        int node = (b << 6) + t;
        beg[node] = b * CAP + ex;
        end[node] = b * CAP + ex + cnt64[t];
        dinv[node] = rsqrtf((float)(cnt64[t] + 1));
    }
    __syncthreads();
    for (int i = t; i < cnt; i += 256) {
        unsigned r = recs[i];
        int pos = atomicAdd(&cur[r & 63u], 1);
        srt[pos] = (int)(r >> 6);
    }
    __syncthreads();
    for (int i = t; i < cnt; i += 256) p[i] = (unsigned)srt[i];
    // scale p0 rows of this bucket's 64 nodes by dinv
    for (int i = t; i < 64 * FF; i += 256) {
        float dv = rsqrtf((float)(cnt64[i / FF] + 1));
        p0[(size_t)b * 64 * FF + i] *= dv;
    }
}

// 3-dim aggregation: q04 = {sum p0[src] + p0[dst], dinv}. p0 L2-resident.
__global__ __launch_bounds__(256) void agg3_kernel(const int* __restrict__ beg,
                                                   const int* __restrict__ end,
                                                   const unsigned* __restrict__ srcs,
                                                   const float* __restrict__ p0,
                                                   const float* __restrict__ dinv,
                                                   float4* __restrict__ q04) {
    int node = blockIdx.x * 256 + threadIdx.x;
    if (node >= NV) return;
    int e = beg[node], en = end[node];
    float a0 = p0[node * 3 + 0], a1 = p0[node * 3 + 1], a2 = p0[node * 3 + 2];
    for (; e + 2 <= en; e += 2) {
        int s0 = srcs[e] * 3, s1 = srcs[e + 1] * 3;
        float u0 = p0[s0], u1 = p0[s0 + 1], u2 = p0[s0 + 2];
        float w0 = p0[s1], w1 = p0[s1 + 1], w2 = p0[s1 + 2];
        a0 += u0 + w0; a1 += u1 + w1; a2 += u2 + w2;
    }
    for (; e < en; ++e) {
        int s = srcs[e] * 3;
        a0 += p0[s]; a1 += p0[s + 1]; a2 += p0[s + 2];
    }
    q04[node] = make_float4(a0, a1, a2, dinv[node]);
}

// p1 = dinv * relu(dinv*(q0@W1) + b1)
__global__ void trans1_kernel(const float4* __restrict__ q04,
                              const float* __restrict__ W1, const float* __restrict__ b1,
                              float* __restrict__ p1) {
    int tid = blockIdx.x * blockDim.x + threadIdx.x;  // NV*DD
    if (tid >= NV * DD) return;
    int node = tid >> 6, d = tid & 63;
    float4 q = q04[node];
    float h = fmaf(q.w, fmaf(q.x, W1[d], fmaf(q.y, W1[64 + d], q.z * W1[128 + d])), b1[d]);
    p1[tid] = q.w * fmaxf(h, 0.f);
}

// ---------------------------------------------------------------------------
// 64-dim aggregation (round-14 proven version): float4-per-lane; 16-lane
// group grp takes edges e0+grp+4k, 2-deep unrolled. Butterfly combine.
// ---------------------------------------------------------------------------
__global__ __launch_bounds__(256) void agg64_kernel(const int* __restrict__ beg,
                                                    const int* __restrict__ end,
                                                    const unsigned* __restrict__ srcs,
                                                    const float* __restrict__ g,
                                                    float* __restrict__ raw) {
    int lane = threadIdx.x & 63;
    int node = (blockIdx.x * blockDim.x + threadIdx.x) >> 6;
    if (node >= NV) return;
    int grp = lane >> 4, sub = lane & 15;
    int e0 = beg[node], en = end[node];
    float4 acc;
    if (grp == 0) {
        acc = ((const float4*)(g + ((size_t)node << 6)))[sub];  // self loop
    } else {
        acc = make_float4(0.f, 0.f, 0.f, 0.f);
    }
    int e = e0 + grp;
    for (; e + 4 < en; e += 8) {
        int s0 = srcs[e], s1 = srcs[e + 4];
        float4 v0 = ((const float4*)(g + ((size_t)s0 << 6)))[sub];
        float4 v1 = ((const float4*)(g + ((size_t)s1 << 6)))[sub];
        acc.x += v0.x + v1.x; acc.y += v0.y + v1.y;
        acc.z += v0.z + v1.z; acc.w += v0.w + v1.w;
    }
    if (e < en) {
        int s = srcs[e];
        float4 v = ((const float4*)(g + ((size_t)s << 6)))[sub];
        acc.x += v.x; acc.y += v.y; acc.z += v.z; acc.w += v.w;
    }
    acc.x += __shfl_xor(acc.x, 16); acc.y += __shfl_xor(acc.y, 16);
    acc.z += __shfl_xor(acc.z, 16); acc.w += __shfl_xor(acc.w, 16);
    acc.x += __shfl_xor(acc.x, 32); acc.y += __shfl_xor(acc.y, 32);
    acc.z += __shfl_xor(acc.z, 32); acc.w += __shfl_xor(acc.w, 32);
    if (grp == 0)
        ((float4*)(raw + ((size_t)node << 6)))[sub] = acc;
}

// ---------------------------------------------------------------------------
// Fused layer-2 transform + partial pooling (round-14 proven): 4x4
// register-tiled GEMM, 0.125 LDS-fetch/FMA, ~50 VGPR.
// ---------------------------------------------------------------------------
__global__ __launch_bounds__(256) void trans2pool_kernel(const float* __restrict__ q1,
                                                         const float* __restrict__ dinv,
                                                         const float* __restrict__ b2,
                                                         const float* __restrict__ W2,
                                                         float* __restrict__ partials) {
    __shared__ float w2s[64 * 64];        // 16 KB, [k][d]
    __shared__ float rT[4][64 * RST];     // 20 KB, per-wave transposed rows [k][r]
    int t = threadIdx.x;
    int lane = t & 63, wvid = t >> 6;
    for (int i = t; i < 64 * 64; i += 256) w2s[i] = W2[i];

    int wid = blockIdx.x * 4 + wvid;
    int n0 = wid * RPW;
    float v[16];
    #pragma unroll
    for (int i = 0; i < 16; ++i) v[i] = q1[((size_t)(n0 + i) << 6) + lane];
    float* rw = rT[wvid];
    #pragma unroll
    for (int r0 = 0; r0 < 16; r0 += 4)
        *(float4*)&rw[lane * RST + r0] = make_float4(v[r0], v[r0 + 1], v[r0 + 2], v[r0 + 3]);
    __syncthreads();

    int ri0 = (lane >> 4) * 4;            // row sub-tile: 0,4,8,12
    int c0 = (lane & 15) * 4;             // col sub-tile: 0..60
    float acc00 = 0.f, acc01 = 0.f, acc02 = 0.f, acc03 = 0.f;
    float acc10 = 0.f, acc11 = 0.f, acc12 = 0.f, acc13 = 0.f;
    float acc20 = 0.f, acc21 = 0.f, acc22 = 0.f, acc23 = 0.f;
    float acc30 = 0.f, acc31 = 0.f, acc32 = 0.f, acc33 = 0.f;
    #pragma unroll 2
    for (int k = 0; k < 64; ++k) {
        float4 w4 = *(const float4*)&w2s[k * 64 + c0];
        float4 r4 = *(const float4*)&rw[k * RST + ri0];
        acc00 = fmaf(r4.x, w4.x, acc00); acc01 = fmaf(r4.x, w4.y, acc01);
        acc02 = fmaf(r4.x, w4.z, acc02); acc03 = fmaf(r4.x, w4.w, acc03);
        acc10 = fmaf(r4.y, w4.x, acc10); acc11 = fmaf(r4.y, w4.y, acc11);
        acc12 = fmaf(r4.y, w4.z, acc12); acc13 = fmaf(r4.y, w4.w, acc13);
        acc20 = fmaf(r4.z, w4.x, acc20); acc21 = fmaf(r4.z, w4.y, acc21);
        acc22 = fmaf(r4.z, w4.z, acc22); acc23 = fmaf(r4.z, w4.w, acc23);
        acc30 = fmaf(r4.w, w4.x, acc30); acc31 = fmaf(r4.w, w4.y, acc31);
        acc32 = fmaf(r4.w, w4.z, acc32); acc33 = fmaf(r4.w, w4.w, acc33);
    }
    float4 bv = *(const float4*)&b2[c0];
    float d0 = dinv[n0 + ri0 + 0], d1 = dinv[n0 + ri0 + 1];
    float d2 = dinv[n0 + ri0 + 2], d3 = dinv[n0 + ri0 + 3];
    float s0 = fmaxf(fmaf(d0, acc00, bv.x), 0.f) + fmaxf(fmaf(d1, acc10, bv.x), 0.f)
             + fmaxf(fmaf(d2, acc20, bv.x), 0.f) + fmaxf(fmaf(d3, acc30, bv.x), 0.f);
    float s1 = fmaxf(fmaf(d0, acc01, bv.y), 0.f) + fmaxf(fmaf(d1, acc11, bv.y), 0.f)
             + fmaxf(fmaf(d2, acc21, bv.y), 0.f) + fmaxf(fmaf(d3, acc31, bv.y), 0.f);
    float s2 = fmaxf(fmaf(d0, acc02, bv.z), 0.f) + fmaxf(fmaf(d1, acc12, bv.z), 0.f)
             + fmaxf(fmaf(d2, acc22, bv.z), 0.f) + fmaxf(fmaf(d3, acc32, bv.z), 0.f);
    float s3 = fmaxf(fmaf(d0, acc03, bv.w), 0.f) + fmaxf(fmaf(d1, acc13, bv.w), 0.f)
             + fmaxf(fmaf(d2, acc23, bv.w), 0.f) + fmaxf(fmaf(d3, acc33, bv.w), 0.f);
    s0 += __shfl_xor(s0, 16); s1 += __shfl_xor(s1, 16);
    s2 += __shfl_xor(s2, 16); s3 += __shfl_xor(s3, 16);
    s0 += __shfl_xor(s0, 32); s1 += __shfl_xor(s1, 32);
    s2 += __shfl_xor(s2, 32); s3 += __shfl_xor(s3, 32);
    if (lane < 16)
        *(float4*)&partials[(size_t)wid * 64 + c0] = make_float4(s0, s1, s2, s3);
}

// Reduce WPG=125 partials per graph (4-way parallel); apply head.
__global__ __launch_bounds__(256) void pool_finish_kernel(const float* __restrict__ partials,
                                                          const float* __restrict__ Wh,
                                                          const float* __restrict__ bh,
                                                          float* __restrict__ out) {
    __shared__ float part[4][64];
    __shared__ float pooled[64];
    int b = blockIdx.x;
    int t = threadIdx.x;
    int d = t & 63, g = t >> 6;
    float s = 0.f;
    for (int c = g; c < WPG; c += 4)
        s += partials[((size_t)(b * WPG + c)) * 64 + d];
    part[g][d] = s;
    __syncthreads();
    if (t < 64)
        pooled[t] = (part[0][t] + part[1][t] + part[2][t] + part[3][t]) * (1.0f / NN);
    __syncthreads();
    if (t < 2) {
        float o = bh[t];
        #pragma unroll 16
        for (int k = 0; k < 64; ++k) o += pooled[k] * Wh[k * 2 + t];
        out[b * 2 + t] = o;
    }
}

extern "C" void kernel_launch(void* const* d_in, const int* in_sizes, int n_in,
                              void* d_out, int out_size, void* d_ws, size_t ws_size,
                              hipStream_t stream) {
    const float* x  = (const float*)d_in[0];
    const int*   ei = (const int*)d_in[1];
    const float* W1 = (const float*)d_in[2];
    const float* b1 = (const float*)d_in[3];
    const float* W2 = (const float*)d_in[4];
    const float* b2 = (const float*)d_in[5];
    const float* Wh = (const float*)d_in[6];
    const float* bh = (const float*)d_in[7];
    float* out = (float*)d_out;

    float* ws   = (float*)d_ws;
    float* bufA = ws;                          // NV*DD  (p1)
    float* bufB = bufA + (size_t)NV * DD;      // NV*DD  (q1)
    float* p0   = bufB + (size_t)NV * DD;      // NV*FF
    float4* q04 = (float4*)(p0 + (size_t)NV * FF);  // NV
    float* dinv = (float*)(q04 + NV);          // NV
    float* partials = dinv + NV;               // NWAVES*64
    unsigned* parts = (unsigned*)(partials + (size_t)NWAVES * 64);  // KB*CAP
    int*   beg  = (int*)(parts + (size_t)KB * CAP);                 // NV
    int*   end  = beg + NV;                    // NV
    int*   gcur = end + NV;                    // KB
    int*   flag = gcur + KB;                   // 1

    // --- setup, then fused edge-partition + temporal-mean ---
    setup_kernel<<<4, 256, 0, stream>>>(ei, flag, gcur);
    part_tmean_kernel<<<NBLKA + TMB, 256, 0, stream>>>(ei, flag, gcur, parts, x, p0);

    // --- per-bucket sort (+ dinv, + p0 scaling) ---
    bsort_kernel<<<KB, 256, 0, stream>>>(parts, gcur, beg, end, dinv, p0);

    // --- Layer 1 aggregation (3-dim gather) -> q04 = {q0, dinv} ---
    agg3_kernel<<<(NV + 255) / 256, 256, 0, stream>>>(beg, end, parts, p0, dinv, q04);

    // --- Layer 1 transform (once per node) ---
    trans1_kernel<<<NV * DD / 256, 256, 0, stream>>>(q04, W1, b1, bufA);

    // --- Layer 2 aggregation ---
    agg64_kernel<<<NV * 64 / 256, 256, 0, stream>>>(beg, end, parts, bufA, bufB);

    // --- Fused layer-2 transform + partial pool (4x4 register-tiled GEMM) ---
    trans2pool_kernel<<<NWAVES / 4, 256, 0, stream>>>(bufB, dinv, b2, W2, partials);

    // --- Head ---
    pool_finish_kernel<<<BB, 256, 0, stream>>>(partials, Wh, bh, out);
}

// Round 18
// 105.414 us; speedup vs baseline: 1.1750x; 1.0878x over previous
//
#include <hip/hip_runtime.h>
#include <hip/hip_bf16.h>
#include <hip/hip_fp16.h>
#include <cstdint>

#define NV 64000      // B*N nodes
#define DD 64         // hidden dim
#define FF 3          // input features
#define NE 1000000    // edges
#define BB 32         // batch (graphs)
#define SS 50         // timesteps
#define NN 2000       // nodes per graph
#define KB 1000       // coarse buckets (dst >> 6), 64 dsts each
#define CAP 1536      // records per bucket region (mean 1000, +17 sigma)
#define NBLKA 250     // partition blocks
#define EPB (NE / NBLKA)  // 4000 edges per partition block
#define TMB 750       // tmean blocks (750*256 == NV*FF)
#define INVALID 0xFFFFFFFFu
#define RPW 16        // rows per wave in trans2pool
#define NWAVES (NV / RPW)   // 4000
#define WPG (NN / RPW)      // 125 partials per graph
#define RST 20        // rT row stride (words): %4==0 keeps b128 alignment

// ---------------------------------------------------------------------------
// Fused setup: zero gcur + int64-vs-int32 detection.
// ---------------------------------------------------------------------------
__global__ __launch_bounds__(256) void setup_kernel(const int* __restrict__ ei,
                                                    int* __restrict__ flag,
                                                    int* __restrict__ gcur) {
    int i = blockIdx.x * 256 + threadIdx.x;
    if (i < KB) gcur[i] = 0;
    if (blockIdx.x == 0) {
        __shared__ int nz;
        if (threadIdx.x == 0) nz = 0;
        __syncthreads();
        int local = 0;
        for (int k = threadIdx.x; k < 4096; k += 256)
            local |= (ei[2 * k + 1] != 0);
        if (local) atomicOr(&nz, 1);
        __syncthreads();
        if (threadIdx.x == 0) *flag = (nz == 0) ? 1 : 0;
    }
}

// ---------------------------------------------------------------------------
// FAT kernel: blocks [0,NBLKA) partition edges (latency/atomic bound);
// blocks [NBLKA,NBLKA+TMB) stream the temporal mean (HBM-bound) -> overlap.
// ---------------------------------------------------------------------------
__global__ __launch_bounds__(256) void part_tmean_kernel(const int* __restrict__ ei32,
                                                         const int* __restrict__ flag,
                                                         int* __restrict__ gcur,
                                                         unsigned* __restrict__ parts,
                                                         const float* __restrict__ x,
                                                         float* __restrict__ p0) {
    __shared__ unsigned recs[EPB];   // 16 KB
    __shared__ int cnt[KB];          // 4 KB
    __shared__ int cur[KB];          // 4 KB
    int t = threadIdx.x;
    if (blockIdx.x >= NBLKA) {
        int tid = (blockIdx.x - NBLKA) * 256 + t;   // < NV*FF
        int nf = tid % (NN * FF);
        int b  = tid / (NN * FF);
        const float* xp = x + (size_t)b * SS * NN * FF + nf;
        float acc = 0.f;
        #pragma unroll
        for (int s = 0; s < SS; ++s) acc += xp[(size_t)s * NN * FF];
        p0[tid] = acc * (1.0f / SS);
        return;
    }
    const long long* ei64 = (const long long*)ei32;
    const int is64 = *flag;
    int e0 = blockIdx.x * EPB;
    for (int i = t; i < KB; i += 256) cnt[i] = 0;
    __syncthreads();
    for (int i = t; i < EPB; i += 256) {
        int e = e0 + i;
        int s, d;
        if (is64) { s = (int)ei64[e]; d = (int)ei64[NE + e]; }
        else      { s = ei32[e];      d = ei32[NE + e]; }
        bool ok = (unsigned)s < NV && (unsigned)d < NV;
        recs[i] = ok ? (((unsigned)s << 16) | (unsigned)d) : INVALID;
        if (ok) atomicAdd(&cnt[d >> 6], 1);
    }
    __syncthreads();
    for (int b = t; b < KB; b += 256) {
        int c = cnt[b];
        cur[b] = (c > 0) ? atomicAdd(&gcur[b], c) : 0;
    }
    __syncthreads();
    for (int i = t; i < EPB; i += 256) {
        unsigned r = recs[i];
        if (r != INVALID) {
            int d = (int)(r & 0xFFFFu);
            int b = d >> 6;
            int pos = atomicAdd(&cur[b], 1);
            if (pos < CAP)
                parts[(size_t)b * CAP + pos] = ((r >> 16) << 6) | (unsigned)(d & 63);
        }
    }
}

// ---------------------------------------------------------------------------
// Per-bucket LDS counting sort -> beg/end + dinv; sorted src ids in place.
// Tail: scale this bucket's 64 p0 rows by dinv.
// ---------------------------------------------------------------------------
__global__ __launch_bounds__(256) void bsort_kernel(unsigned* __restrict__ parts,
                                                    const int* __restrict__ gcur,
                                                    int* __restrict__ beg,
                                                    int* __restrict__ end,
                                                    float* __restrict__ dinv,
                                                    float* __restrict__ p0) {
    __shared__ unsigned recs[CAP];
    __shared__ int srt[CAP];
    __shared__ int cnt64[64];
    __shared__ int pref[64];
    __shared__ int cur[64];
    int b = blockIdx.x, t = threadIdx.x;
    int cnt = min(gcur[b], CAP);
    unsigned* p = parts + (size_t)b * CAP;
    if (t < 64) cnt64[t] = 0;
    __syncthreads();
    for (int i = t; i < cnt; i += 256) {
        unsigned r = p[i];
        recs[i] = r;
        atomicAdd(&cnt64[r & 63u], 1);
    }
    __syncthreads();
    if (t < 64) pref[t] = cnt64[t];
    __syncthreads();
    #pragma unroll
    for (int off = 1; off < 64; off <<= 1) {
        int v = (t < 64 && t >= off) ? pref[t - off] : 0;
        __syncthreads();
        if (t < 64) pref[t] += v;
        __syncthreads();
    }
    if (t < 64) {
        int ex = pref[t] - cnt64[t];
        cur[t] = ex;
        int node = (b << 6) + t;
        beg[node] = b * CAP + ex;
        end[node] = b * CAP + ex + cnt64[t];
        dinv[node] = rsqrtf((float)(cnt64[t] + 1));
    }
    __syncthreads();
    for (int i = t; i < cnt; i += 256) {
        unsigned r = recs[i];
        int pos = atomicAdd(&cur[r & 63u], 1);
        srt[pos] = (int)(r >> 6);
    }
    __syncthreads();
    for (int i = t; i < cnt; i += 256) p[i] = (unsigned)srt[i];
    for (int i = t; i < 64 * FF; i += 256) {
        float dv = rsqrtf((float)(cnt64[i / FF] + 1));
        p0[(size_t)b * 64 * FF + i] *= dv;
    }
}

// 3-dim aggregation: q04 = {sum p0[src] + p0[dst], dinv}. p0 L2-resident.
__global__ __launch_bounds__(256) void agg3_kernel(const int* __restrict__ beg,
                                                   const int* __restrict__ end,
                                                   const unsigned* __restrict__ srcs,
                                                   const float* __restrict__ p0,
                                                   const float* __restrict__ dinv,
                                                   float4* __restrict__ q04) {
    int node = blockIdx.x * 256 + threadIdx.x;
    if (node >= NV) return;
    int e = beg[node], en = end[node];
    float a0 = p0[node * 3 + 0], a1 = p0[node * 3 + 1], a2 = p0[node * 3 + 2];
    for (; e + 2 <= en; e += 2) {
        int s0 = srcs[e] * 3, s1 = srcs[e + 1] * 3;
        float u0 = p0[s0], u1 = p0[s0 + 1], u2 = p0[s0 + 2];
        float w0 = p0[s1], w1 = p0[s1 + 1], w2 = p0[s1 + 2];
        a0 += u0 + w0; a1 += u1 + w1; a2 += u2 + w2;
    }
    for (; e < en; ++e) {
        int s = srcs[e] * 3;
        a0 += p0[s]; a1 += p0[s + 1]; a2 += p0[s + 2];
    }
    q04[node] = make_float4(a0, a1, a2, dinv[node]);
}

// p1 = fp16(dinv * relu(dinv*(q0@W1) + b1)) -- halves layer-2 gather bytes.
__global__ void trans1_kernel(const float4* __restrict__ q04,
                              const float* __restrict__ W1, const float* __restrict__ b1,
                              __half2* __restrict__ p1h) {
    int tid = blockIdx.x * blockDim.x + threadIdx.x;  // NV*32
    if (tid >= NV * 32) return;
    int node = tid >> 5, j = tid & 31;
    int d0 = 2 * j, d1 = 2 * j + 1;
    float4 q = q04[node];
    float h0 = fmaf(q.w, fmaf(q.x, W1[d0], fmaf(q.y, W1[64 + d0], q.z * W1[128 + d0])), b1[d0]);
    float h1 = fmaf(q.w, fmaf(q.x, W1[d1], fmaf(q.y, W1[64 + d1], q.z * W1[128 + d1])), b1[d1]);
    p1h[tid] = __floats2half2_rn(q.w * fmaxf(h0, 0.f), q.w * fmaxf(h1, 0.f));
}

// ---------------------------------------------------------------------------
// 64-dim aggregation v4, fp16 rows: row = 128 B = 8 lanes x 16 B. One wave
// per dst node; 8-lane group grp takes edges e0+grp+8k (2-deep unrolled);
// lane sub gathers one uint4 (8 halfs, dims [8*sub,8*sub+8)), accumulates
// fp32. Butterfly (^8,^16,^32) combines the 8 groups; grp 0 stores fp32 row.
// Halves both logical gather volume and L3->L2 fills vs fp32.
// ---------------------------------------------------------------------------
__global__ __launch_bounds__(256) void agg64_kernel(const int* __restrict__ beg,
                                                    const int* __restrict__ end,
                                                    const unsigned* __restrict__ srcs,
                                                    const __half2* __restrict__ g,
                                                    float* __restrict__ raw) {
    int lane = threadIdx.x & 63;
    int node = (blockIdx.x * blockDim.x + threadIdx.x) >> 6;
    if (node >= NV) return;
    int grp = lane >> 3, sub = lane & 7;
    const uint4* base = (const uint4*)g;   // 8 uint4 per node row
    float a0 = 0.f, a1 = 0.f, a2 = 0.f, a3 = 0.f;
    float a4 = 0.f, a5 = 0.f, a6 = 0.f, a7 = 0.f;
#define UNPACK_ADD(v) do { float2 f_;                                         \
        f_ = __half22float2(*(const __half2*)&(v).x); a0 += f_.x; a1 += f_.y; \
        f_ = __half22float2(*(const __half2*)&(v).y); a2 += f_.x; a3 += f_.y; \
        f_ = __half22float2(*(const __half2*)&(v).z); a4 += f_.x; a5 += f_.y; \
        f_ = __half22float2(*(const __half2*)&(v).w); a6 += f_.x; a7 += f_.y; } while (0)
    if (grp == 0) {
        uint4 v = base[((size_t)node << 3) + sub];   // self loop
        UNPACK_ADD(v);
    }
    int e = beg[node] + grp, en = end[node];
    for (; e + 8 < en; e += 16) {
        uint4 v0 = base[((size_t)srcs[e] << 3) + sub];
        uint4 v1 = base[((size_t)srcs[e + 8] << 3) + sub];
        UNPACK_ADD(v0);
        UNPACK_ADD(v1);
    }
    if (e < en) {
        uint4 v = base[((size_t)srcs[e] << 3) + sub];
        UNPACK_ADD(v);
    }
#undef UNPACK_ADD
    #pragma unroll
    for (int m = 8; m <= 32; m <<= 1) {
        a0 += __shfl_xor(a0, m); a1 += __shfl_xor(a1, m);
        a2 += __shfl_xor(a2, m); a3 += __shfl_xor(a3, m);
        a4 += __shfl_xor(a4, m); a5 += __shfl_xor(a5, m);
        a6 += __shfl_xor(a6, m); a7 += __shfl_xor(a7, m);
    }
    if (grp == 0) {
        float4* out = (float4*)(raw + ((size_t)node << 6));
        out[sub * 2 + 0] = make_float4(a0, a1, a2, a3);
        out[sub * 2 + 1] = make_float4(a4, a5, a6, a7);
    }
}

// ---------------------------------------------------------------------------
// Fused layer-2 transform + partial pooling (round-14 proven): 4x4
// register-tiled GEMM, 0.125 LDS-fetch/FMA, ~50 VGPR.
// ---------------------------------------------------------------------------
__global__ __launch_bounds__(256) void trans2pool_kernel(const float* __restrict__ q1,
                                                         const float* __restrict__ dinv,
                                                         const float* __restrict__ b2,
                                                         const float* __restrict__ W2,
                                                         float* __restrict__ partials) {
    __shared__ float w2s[64 * 64];        // 16 KB, [k][d]
    __shared__ float rT[4][64 * RST];     // 20 KB, per-wave transposed rows [k][r]
    int t = threadIdx.x;
    int lane = t & 63, wvid = t >> 6;
    for (int i = t; i < 64 * 64; i += 256) w2s[i] = W2[i];

    int wid = blockIdx.x * 4 + wvid;
    int n0 = wid * RPW;
    float v[16];
    #pragma unroll
    for (int i = 0; i < 16; ++i) v[i] = q1[((size_t)(n0 + i) << 6) + lane];
    float* rw = rT[wvid];
    #pragma unroll
    for (int r0 = 0; r0 < 16; r0 += 4)
        *(float4*)&rw[lane * RST + r0] = make_float4(v[r0], v[r0 + 1], v[r0 + 2], v[r0 + 3]);
    __syncthreads();

    int ri0 = (lane >> 4) * 4;            // row sub-tile: 0,4,8,12
    int c0 = (lane & 15) * 4;             // col sub-tile: 0..60
    float acc00 = 0.f, acc01 = 0.f, acc02 = 0.f, acc03 = 0.f;
    float acc10 = 0.f, acc11 = 0.f, acc12 = 0.f, acc13 = 0.f;
    float acc20 = 0.f, acc21 = 0.f, acc22 = 0.f, acc23 = 0.f;
    float acc30 = 0.f, acc31 = 0.f, acc32 = 0.f, acc33 = 0.f;
    #pragma unroll 2
    for (int k = 0; k < 64; ++k) {
        float4 w4 = *(const float4*)&w2s[k * 64 + c0];
        float4 r4 = *(const float4*)&rw[k * RST + ri0];
        acc00 = fmaf(r4.x, w4.x, acc00); acc01 = fmaf(r4.x, w4.y, acc01);
        acc02 = fmaf(r4.x, w4.z, acc02); acc03 = fmaf(r4.x, w4.w, acc03);
        acc10 = fmaf(r4.y, w4.x, acc10); acc11 = fmaf(r4.y, w4.y, acc11);
        acc12 = fmaf(r4.y, w4.z, acc12); acc13 = fmaf(r4.y, w4.w, acc13);
        acc20 = fmaf(r4.z, w4.x, acc20); acc21 = fmaf(r4.z, w4.y, acc21);
        acc22 = fmaf(r4.z, w4.z, acc22); acc23 = fmaf(r4.z, w4.w, acc23);
        acc30 = fmaf(r4.w, w4.x, acc30); acc31 = fmaf(r4.w, w4.y, acc31);
        acc32 = fmaf(r4.w, w4.z, acc32); acc33 = fmaf(r4.w, w4.w, acc33);
    }
    float4 bv = *(const float4*)&b2[c0];
    float d0 = dinv[n0 + ri0 + 0], d1 = dinv[n0 + ri0 + 1];
    float d2 = dinv[n0 + ri0 + 2], d3 = dinv[n0 + ri0 + 3];
    float s0 = fmaxf(fmaf(d0, acc00, bv.x), 0.f) + fmaxf(fmaf(d1, acc10, bv.x), 0.f)
             + fmaxf(fmaf(d2, acc20, bv.x), 0.f) + fmaxf(fmaf(d3, acc30, bv.x), 0.f);
    float s1 = fmaxf(fmaf(d0, acc01, bv.y), 0.f) + fmaxf(fmaf(d1, acc11, bv.y), 0.f)
             + fmaxf(fmaf(d2, acc21, bv.y), 0.f) + fmaxf(fmaf(d3, acc31, bv.y), 0.f);
    float s2 = fmaxf(fmaf(d0, acc02, bv.z), 0.f) + fmaxf(fmaf(d1, acc12, bv.z), 0.f)
             + fmaxf(fmaf(d2, acc22, bv.z), 0.f) + fmaxf(fmaf(d3, acc32, bv.z), 0.f);
    float s3 = fmaxf(fmaf(d0, acc03, bv.w), 0.f) + fmaxf(fmaf(d1, acc13, bv.w), 0.f)
             + fmaxf(fmaf(d2, acc23, bv.w), 0.f) + fmaxf(fmaf(d3, acc33, bv.w), 0.f);
    s0 += __shfl_xor(s0, 16); s1 += __shfl_xor(s1, 16);
    s2 += __shfl_xor(s2, 16); s3 += __shfl_xor(s3, 16);
    s0 += __shfl_xor(s0, 32); s1 += __shfl_xor(s1, 32);
    s2 += __shfl_xor(s2, 32); s3 += __shfl_xor(s3, 32);
    if (lane < 16)
        *(float4*)&partials[(size_t)wid * 64 + c0] = make_float4(s0, s1, s2, s3);
}

// Reduce WPG=125 partials per graph (4-way parallel); apply head.
__global__ __launch_bounds__(256) void pool_finish_kernel(const float* __restrict__ partials,
                                                          const float* __restrict__ Wh,
                                                          const float* __restrict__ bh,
                                                          float* __restrict__ out) {
    __shared__ float part[4][64];
    __shared__ float pooled[64];
    int b = blockIdx.x;
    int t = threadIdx.x;
    int d = t & 63, g = t >> 6;
    float s = 0.f;
    for (int c = g; c < WPG; c += 4)
        s += partials[((size_t)(b * WPG + c)) * 64 + d];
    part[g][d] = s;
    __syncthreads();
    if (t < 64)
        pooled[t] = (part[0][t] + part[1][t] + part[2][t] + part[3][t]) * (1.0f / NN);
    __syncthreads();
    if (t < 2) {
        float o = bh[t];
        #pragma unroll 16
        for (int k = 0; k < 64; ++k) o += pooled[k] * Wh[k * 2 + t];
        out[b * 2 + t] = o;
    }
}

extern "C" void kernel_launch(void* const* d_in, const int* in_sizes, int n_in,
                              void* d_out, int out_size, void* d_ws, size_t ws_size,
                              hipStream_t stream) {
    const float* x  = (const float*)d_in[0];
    const int*   ei = (const int*)d_in[1];
    const float* W1 = (const float*)d_in[2];
    const float* b1 = (const float*)d_in[3];
    const float* W2 = (const float*)d_in[4];
    const float* b2 = (const float*)d_in[5];
    const float* Wh = (const float*)d_in[6];
    const float* bh = (const float*)d_in[7];
    float* out = (float*)d_out;

    float* ws   = (float*)d_ws;
    float* bufA = ws;                          // NV*DD floats (p1h uses half = 8 MB)
    float* bufB = bufA + (size_t)NV * DD;      // NV*DD  (q1, fp32)
    float* p0   = bufB + (size_t)NV * DD;      // NV*FF
    float4* q04 = (float4*)(p0 + (size_t)NV * FF);  // NV
    float* dinv = (float*)(q04 + NV);          // NV
    float* partials = dinv + NV;               // NWAVES*64
    unsigned* parts = (unsigned*)(partials + (size_t)NWAVES * 64);  // KB*CAP
    int*   beg  = (int*)(parts + (size_t)KB * CAP);                 // NV
    int*   end  = beg + NV;                    // NV
    int*   gcur = end + NV;                    // KB
    int*   flag = gcur + KB;                   // 1
    __half2* p1h = (__half2*)bufA;             // NV*32 half2 (8 MB, 16B-aligned)

    // --- setup, then fused edge-partition + temporal-mean ---
    setup_kernel<<<4, 256, 0, stream>>>(ei, flag, gcur);
    part_tmean_kernel<<<NBLKA + TMB, 256, 0, stream>>>(ei, flag, gcur, parts, x, p0);

    // --- per-bucket sort (+ dinv, + p0 scaling) ---
    bsort_kernel<<<KB, 256, 0, stream>>>(parts, gcur, beg, end, dinv, p0);

    // --- Layer 1 aggregation (3-dim gather) -> q04 = {q0, dinv} ---
    agg3_kernel<<<(NV + 255) / 256, 256, 0, stream>>>(beg, end, parts, p0, dinv, q04);

    // --- Layer 1 transform -> fp16 p1 ---
    trans1_kernel<<<NV * 32 / 256, 256, 0, stream>>>(q04, W1, b1, p1h);

    // --- Layer 2 aggregation (fp16 gather, fp32 accumulate) ---
    agg64_kernel<<<NV * 64 / 256, 256, 0, stream>>>(beg, end, parts, p1h, bufB);

    // --- Fused layer-2 transform + partial pool (4x4 register-tiled GEMM) ---
    trans2pool_kernel<<<NWAVES / 4, 256, 0, stream>>>(bufB, dinv, b2, W2, partials);

    // --- Head ---
    pool_finish_kernel<<<BB, 256, 0, stream>>>(partials, Wh, bh, out);
}

// Round 19
// 101.202 us; speedup vs baseline: 1.2239x; 1.0416x over previous
//
#include <hip/hip_runtime.h>
#include <hip/hip_bf16.h>
#include <hip/hip_fp16.h>
#include <cstdint>

#define NV 64000      // B*N nodes
#define DD 64         // hidden dim
#define FF 3          // input features
#define NE 1000000    // edges
#define BB 32         // batch (graphs)
#define SS 50         // timesteps
#define NN 2000       // nodes per graph
#define KB 1000       // coarse buckets (dst >> 6), 64 dsts each
#define CAP 1536      // records per bucket region (mean 1000, +17 sigma)
#define NBLKA 250     // partition blocks
#define EPB (NE / NBLKA)  // 4000 edges per partition block
#define TMB 750       // tmean blocks (750*256 == NV*FF)
#define INVALID 0xFFFFFFFFu
#define RPW 16        // rows per wave in trans2pool
#define NWAVES (NV / RPW)   // 4000
#define WPG (NN / RPW)      // 125 partials per graph
#define RST 20        // rT row stride (words): %4==0 keeps b128 alignment

// ---------------------------------------------------------------------------
// FAT kernel: blocks [0,NBLKA) partition edges (latency/atomic bound);
// blocks [NBLKA,NBLKA+TMB) stream the temporal mean (HBM-bound) -> overlap.
// int64-vs-int32 detection inlined per part-block (first 4096 odd words are
// L2-hot after block 0); gcur pre-zeroed by hipMemsetAsync.
// ---------------------------------------------------------------------------
__global__ __launch_bounds__(256) void part_tmean_kernel(const int* __restrict__ ei32,
                                                         int* __restrict__ gcur,
                                                         unsigned* __restrict__ parts,
                                                         const float* __restrict__ x,
                                                         float* __restrict__ p0) {
    int t = threadIdx.x;
    if (blockIdx.x >= NBLKA) {
        int tid = (blockIdx.x - NBLKA) * 256 + t;   // < NV*FF
        int nf = tid % (NN * FF);
        int b  = tid / (NN * FF);
        const float* xp = x + (size_t)b * SS * NN * FF + nf;
        float acc = 0.f;
        #pragma unroll
        for (int s = 0; s < SS; ++s) acc += xp[(size_t)s * NN * FF];
        p0[tid] = acc * (1.0f / SS);
        return;
    }
    __shared__ unsigned recs[EPB];   // 16 KB
    __shared__ int cnt[KB];          // 4 KB
    __shared__ int cur[KB];          // 4 KB
    __shared__ int nz;
    if (t == 0) nz = 0;
    for (int i = t; i < KB; i += 256) cnt[i] = 0;
    __syncthreads();
    int local = 0;
    for (int k = t; k < 4096; k += 256) local |= (ei32[2 * k + 1] != 0);
    if (local) atomicOr(&nz, 1);
    __syncthreads();
    const int is64 = (nz == 0);
    const long long* ei64 = (const long long*)ei32;
    int e0 = blockIdx.x * EPB;
    for (int i = t; i < EPB; i += 256) {
        int e = e0 + i;
        int s, d;
        if (is64) { s = (int)ei64[e]; d = (int)ei64[NE + e]; }
        else      { s = ei32[e];      d = ei32[NE + e]; }
        bool ok = (unsigned)s < NV && (unsigned)d < NV;
        recs[i] = ok ? (((unsigned)s << 16) | (unsigned)d) : INVALID;
        if (ok) atomicAdd(&cnt[d >> 6], 1);
    }
    __syncthreads();
    for (int b = t; b < KB; b += 256) {
        int c = cnt[b];
        cur[b] = (c > 0) ? atomicAdd(&gcur[b], c) : 0;
    }
    __syncthreads();
    for (int i = t; i < EPB; i += 256) {
        unsigned r = recs[i];
        if (r != INVALID) {
            int d = (int)(r & 0xFFFFu);
            int b = d >> 6;
            int pos = atomicAdd(&cur[b], 1);
            if (pos < CAP)
                parts[(size_t)b * CAP + pos] = ((r >> 16) << 6) | (unsigned)(d & 63);
        }
    }
}

// ---------------------------------------------------------------------------
// Per-bucket LDS counting sort -> beg/end + dinv; sorted src ids in place.
// Tail: scale this bucket's 64 p0 rows by dinv.
// ---------------------------------------------------------------------------
__global__ __launch_bounds__(256) void bsort_kernel(unsigned* __restrict__ parts,
                                                    const int* __restrict__ gcur,
                                                    int* __restrict__ beg,
                                                    int* __restrict__ end,
                                                    float* __restrict__ dinv,
                                                    float* __restrict__ p0) {
    __shared__ unsigned recs[CAP];
    __shared__ int srt[CAP];
    __shared__ int cnt64[64];
    __shared__ int pref[64];
    __shared__ int cur[64];
    int b = blockIdx.x, t = threadIdx.x;
    int cnt = min(gcur[b], CAP);
    unsigned* p = parts + (size_t)b * CAP;
    if (t < 64) cnt64[t] = 0;
    __syncthreads();
    for (int i = t; i < cnt; i += 256) {
        unsigned r = p[i];
        recs[i] = r;
        atomicAdd(&cnt64[r & 63u], 1);
    }
    __syncthreads();
    if (t < 64) pref[t] = cnt64[t];
    __syncthreads();
    #pragma unroll
    for (int off = 1; off < 64; off <<= 1) {
        int v = (t < 64 && t >= off) ? pref[t - off] : 0;
        __syncthreads();
        if (t < 64) pref[t] += v;
        __syncthreads();
    }
    if (t < 64) {
        int ex = pref[t] - cnt64[t];
        cur[t] = ex;
        int node = (b << 6) + t;
        beg[node] = b * CAP + ex;
        end[node] = b * CAP + ex + cnt64[t];
        dinv[node] = rsqrtf((float)(cnt64[t] + 1));
    }
    __syncthreads();
    for (int i = t; i < cnt; i += 256) {
        unsigned r = recs[i];
        int pos = atomicAdd(&cur[r & 63u], 1);
        srt[pos] = (int)(r >> 6);
    }
    __syncthreads();
    for (int i = t; i < cnt; i += 256) p[i] = (unsigned)srt[i];
    for (int i = t; i < 64 * FF; i += 256) {
        float dv = rsqrtf((float)(cnt64[i / FF] + 1));
        p0[(size_t)b * 64 * FF + i] *= dv;
    }
}

// ---------------------------------------------------------------------------
// FUSED layer-1 aggregation + transform. Block = 256 nodes.
// Phase 1: per-thread 3-dim gather (p0 L2-resident) -> LDS float4 {q0,dinv}.
// Phase 2: coalesced p1h production: thread t handles output pair j = t&31
// for 32 nodes (W1 coefficients loop-invariant per thread, hoisted).
// ---------------------------------------------------------------------------
__global__ __launch_bounds__(256) void agg3trans_kernel(const int* __restrict__ beg,
                                                        const int* __restrict__ end,
                                                        const unsigned* __restrict__ srcs,
                                                        const float* __restrict__ p0,
                                                        const float* __restrict__ dinv,
                                                        const float* __restrict__ W1,
                                                        const float* __restrict__ b1,
                                                        __half2* __restrict__ p1h) {
    __shared__ float4 q4s[256];
    int t = threadIdx.x;
    int node = blockIdx.x * 256 + t;
    int e = beg[node], en = end[node];
    float a0 = p0[node * 3 + 0], a1 = p0[node * 3 + 1], a2 = p0[node * 3 + 2];
    for (; e + 2 <= en; e += 2) {
        int s0 = srcs[e] * 3, s1 = srcs[e + 1] * 3;
        float u0 = p0[s0], u1 = p0[s0 + 1], u2 = p0[s0 + 2];
        float w0 = p0[s1], w1 = p0[s1 + 1], w2 = p0[s1 + 2];
        a0 += u0 + w0; a1 += u1 + w1; a2 += u2 + w2;
    }
    for (; e < en; ++e) {
        int s = srcs[e] * 3;
        a0 += p0[s]; a1 += p0[s + 1]; a2 += p0[s + 2];
    }
    q4s[t] = make_float4(a0, a1, a2, dinv[node]);
    __syncthreads();
    int j = t & 31;
    int d0 = 2 * j, d1 = d0 + 1;
    float w00 = W1[d0], w10 = W1[64 + d0], w20 = W1[128 + d0], bb0 = b1[d0];
    float w01 = W1[d1], w11 = W1[64 + d1], w21 = W1[128 + d1], bb1 = b1[d1];
    size_t base = (size_t)blockIdx.x * 256 * 32;
    #pragma unroll 8
    for (int i = 0; i < 32; ++i) {
        int idx = t + 256 * i;
        float4 q = q4s[idx >> 5];
        float h0 = fmaf(q.w, fmaf(q.x, w00, fmaf(q.y, w10, q.z * w20)), bb0);
        float h1 = fmaf(q.w, fmaf(q.x, w01, fmaf(q.y, w11, q.z * w21)), bb1);
        p1h[base + idx] = __floats2half2_rn(q.w * fmaxf(h0, 0.f), q.w * fmaxf(h1, 0.f));
    }
}

// ---------------------------------------------------------------------------
// 64-dim aggregation, fp16 in / fp16 out: row = 128 B = 8 lanes x 16 B.
// 8-lane group grp takes edges e0+grp+8k (2-deep); fp32 accumulate;
// butterfly (^8,^16,^32); grp 0 packs to half2 and stores 16 B.
// ---------------------------------------------------------------------------
__global__ __launch_bounds__(256) void agg64_kernel(const int* __restrict__ beg,
                                                    const int* __restrict__ end,
                                                    const unsigned* __restrict__ srcs,
                                                    const __half2* __restrict__ g,
                                                    __half2* __restrict__ q1h) {
    int lane = threadIdx.x & 63;
    int node = (blockIdx.x * blockDim.x + threadIdx.x) >> 6;
    if (node >= NV) return;
    int grp = lane >> 3, sub = lane & 7;
    const uint4* base = (const uint4*)g;   // 8 uint4 per node row
    float a0 = 0.f, a1 = 0.f, a2 = 0.f, a3 = 0.f;
    float a4 = 0.f, a5 = 0.f, a6 = 0.f, a7 = 0.f;
#define UNPACK_ADD(v) do { float2 f_;                                         \
        f_ = __half22float2(*(const __half2*)&(v).x); a0 += f_.x; a1 += f_.y; \
        f_ = __half22float2(*(const __half2*)&(v).y); a2 += f_.x; a3 += f_.y; \
        f_ = __half22float2(*(const __half2*)&(v).z); a4 += f_.x; a5 += f_.y; \
        f_ = __half22float2(*(const __half2*)&(v).w); a6 += f_.x; a7 += f_.y; } while (0)
    if (grp == 0) {
        uint4 v = base[((size_t)node << 3) + sub];   // self loop
        UNPACK_ADD(v);
    }
    int e = beg[node] + grp, en = end[node];
    for (; e + 8 < en; e += 16) {
        uint4 v0 = base[((size_t)srcs[e] << 3) + sub];
        uint4 v1 = base[((size_t)srcs[e + 8] << 3) + sub];
        UNPACK_ADD(v0);
        UNPACK_ADD(v1);
    }
    if (e < en) {
        uint4 v = base[((size_t)srcs[e] << 3) + sub];
        UNPACK_ADD(v);
    }
#undef UNPACK_ADD
    #pragma unroll
    for (int m = 8; m <= 32; m <<= 1) {
        a0 += __shfl_xor(a0, m); a1 += __shfl_xor(a1, m);
        a2 += __shfl_xor(a2, m); a3 += __shfl_xor(a3, m);
        a4 += __shfl_xor(a4, m); a5 += __shfl_xor(a5, m);
        a6 += __shfl_xor(a6, m); a7 += __shfl_xor(a7, m);
    }
    if (grp == 0) {
        uint4 o;
        *(__half2*)&o.x = __floats2half2_rn(a0, a1);
        *(__half2*)&o.y = __floats2half2_rn(a2, a3);
        *(__half2*)&o.z = __floats2half2_rn(a4, a5);
        *(__half2*)&o.w = __floats2half2_rn(a6, a7);
        ((uint4*)q1h)[((size_t)node << 3) + sub] = o;
    }
}

// ---------------------------------------------------------------------------
// Fused layer-2 transform + partial pooling: 4x4 register-tiled GEMM,
// 0.125 LDS-fetch/FMA, fp16 q1 input (converted to fp32 in LDS staging).
// ---------------------------------------------------------------------------
__global__ __launch_bounds__(256) void trans2pool_kernel(const __half* __restrict__ q1h,
                                                         const float* __restrict__ dinv,
                                                         const float* __restrict__ b2,
                                                         const float* __restrict__ W2,
                                                         float* __restrict__ partials) {
    __shared__ float w2s[64 * 64];        // 16 KB, [k][d]
    __shared__ float rT[4][64 * RST];     // 20 KB, per-wave transposed rows [k][r]
    int t = threadIdx.x;
    int lane = t & 63, wvid = t >> 6;
    for (int i = t; i < 64 * 64; i += 256) w2s[i] = W2[i];

    int wid = blockIdx.x * 4 + wvid;
    int n0 = wid * RPW;
    float v[16];
    #pragma unroll
    for (int i = 0; i < 16; ++i)
        v[i] = __half2float(q1h[((size_t)(n0 + i) << 6) + lane]);
    float* rw = rT[wvid];
    #pragma unroll
    for (int r0 = 0; r0 < 16; r0 += 4)
        *(float4*)&rw[lane * RST + r0] = make_float4(v[r0], v[r0 + 1], v[r0 + 2], v[r0 + 3]);
    __syncthreads();

    int ri0 = (lane >> 4) * 4;            // row sub-tile: 0,4,8,12
    int c0 = (lane & 15) * 4;             // col sub-tile: 0..60
    float acc00 = 0.f, acc01 = 0.f, acc02 = 0.f, acc03 = 0.f;
    float acc10 = 0.f, acc11 = 0.f, acc12 = 0.f, acc13 = 0.f;
    float acc20 = 0.f, acc21 = 0.f, acc22 = 0.f, acc23 = 0.f;
    float acc30 = 0.f, acc31 = 0.f, acc32 = 0.f, acc33 = 0.f;
    #pragma unroll 2
    for (int k = 0; k < 64; ++k) {
        float4 w4 = *(const float4*)&w2s[k * 64 + c0];
        float4 r4 = *(const float4*)&rw[k * RST + ri0];
        acc00 = fmaf(r4.x, w4.x, acc00); acc01 = fmaf(r4.x, w4.y, acc01);
        acc02 = fmaf(r4.x, w4.z, acc02); acc03 = fmaf(r4.x, w4.w, acc03);
        acc10 = fmaf(r4.y, w4.x, acc10); acc11 = fmaf(r4.y, w4.y, acc11);
        acc12 = fmaf(r4.y, w4.z, acc12); acc13 = fmaf(r4.y, w4.w, acc13);
        acc20 = fmaf(r4.z, w4.x, acc20); acc21 = fmaf(r4.z, w4.y, acc21);
        acc22 = fmaf(r4.z, w4.z, acc22); acc23 = fmaf(r4.z, w4.w, acc23);
        acc30 = fmaf(r4.w, w4.x, acc30); acc31 = fmaf(r4.w, w4.y, acc31);
        acc32 = fmaf(r4.w, w4.z, acc32); acc33 = fmaf(r4.w, w4.w, acc33);
    }
    float4 bv = *(const float4*)&b2[c0];
    float d0 = dinv[n0 + ri0 + 0], d1 = dinv[n0 + ri0 + 1];
    float d2 = dinv[n0 + ri0 + 2], d3 = dinv[n0 + ri0 + 3];
    float s0 = fmaxf(fmaf(d0, acc00, bv.x), 0.f) + fmaxf(fmaf(d1, acc10, bv.x), 0.f)
             + fmaxf(fmaf(d2, acc20, bv.x), 0.f) + fmaxf(fmaf(d3, acc30, bv.x), 0.f);
    float s1 = fmaxf(fmaf(d0, acc01, bv.y), 0.f) + fmaxf(fmaf(d1, acc11, bv.y), 0.f)
             + fmaxf(fmaf(d2, acc21, bv.y), 0.f) + fmaxf(fmaf(d3, acc31, bv.y), 0.f);
    float s2 = fmaxf(fmaf(d0, acc02, bv.z), 0.f) + fmaxf(fmaf(d1, acc12, bv.z), 0.f)
             + fmaxf(fmaf(d2, acc22, bv.z), 0.f) + fmaxf(fmaf(d3, acc32, bv.z), 0.f);
    float s3 = fmaxf(fmaf(d0, acc03, bv.w), 0.f) + fmaxf(fmaf(d1, acc13, bv.w), 0.f)
             + fmaxf(fmaf(d2, acc23, bv.w), 0.f) + fmaxf(fmaf(d3, acc33, bv.w), 0.f);
    s0 += __shfl_xor(s0, 16); s1 += __shfl_xor(s1, 16);
    s2 += __shfl_xor(s2, 16); s3 += __shfl_xor(s3, 16);
    s0 += __shfl_xor(s0, 32); s1 += __shfl_xor(s1, 32);
    s2 += __shfl_xor(s2, 32); s3 += __shfl_xor(s3, 32);
    if (lane < 16)
        *(float4*)&partials[(size_t)wid * 64 + c0] = make_float4(s0, s1, s2, s3);
}

// Reduce WPG=125 partials per graph (4-way parallel); apply head.
__global__ __launch_bounds__(256) void pool_finish_kernel(const float* __restrict__ partials,
                                                          const float* __restrict__ Wh,
                                                          const float* __restrict__ bh,
                                                          float* __restrict__ out) {
    __shared__ float part[4][64];
    __shared__ float pooled[64];
    int b = blockIdx.x;
    int t = threadIdx.x;
    int d = t & 63, g = t >> 6;
    float s = 0.f;
    for (int c = g; c < WPG; c += 4)
        s += partials[((size_t)(b * WPG + c)) * 64 + d];
    part[g][d] = s;
    __syncthreads();
    if (t < 64)
        pooled[t] = (part[0][t] + part[1][t] + part[2][t] + part[3][t]) * (1.0f / NN);
    __syncthreads();
    if (t < 2) {
        float o = bh[t];
        #pragma unroll 16
        for (int k = 0; k < 64; ++k) o += pooled[k] * Wh[k * 2 + t];
        out[b * 2 + t] = o;
    }
}

extern "C" void kernel_launch(void* const* d_in, const int* in_sizes, int n_in,
                              void* d_out, int out_size, void* d_ws, size_t ws_size,
                              hipStream_t stream) {
    const float* x  = (const float*)d_in[0];
    const int*   ei = (const int*)d_in[1];
    const float* W1 = (const float*)d_in[2];
    const float* b1 = (const float*)d_in[3];
    const float* W2 = (const float*)d_in[4];
    const float* b2 = (const float*)d_in[5];
    const float* Wh = (const float*)d_in[6];
    const float* bh = (const float*)d_in[7];
    float* out = (float*)d_out;

    float* ws   = (float*)d_ws;
    float* bufA = ws;                          // NV*DD floats reserved (p1h: 8 MB)
    float* bufB = bufA + (size_t)NV * DD;      // NV*DD floats reserved (q1h: 8 MB)
    float* p0   = bufB + (size_t)NV * DD;      // NV*FF
    float* dinv = p0 + (size_t)NV * FF;        // NV
    float* partials = dinv + NV;               // NWAVES*64
    unsigned* parts = (unsigned*)(partials + (size_t)NWAVES * 64);  // KB*CAP
    int*   beg  = (int*)(parts + (size_t)KB * CAP);                 // NV
    int*   end  = beg + NV;                    // NV
    int*   gcur = end + NV;                    // KB
    __half2* p1h = (__half2*)bufA;             // NV*32 half2 (8 MB)
    __half2* q1h = (__half2*)bufB;             // NV*32 half2 (8 MB)

    // --- zero bucket cursors (async, capture-safe), then fat part+tmean ---
    hipMemsetAsync(gcur, 0, KB * sizeof(int), stream);
    part_tmean_kernel<<<NBLKA + TMB, 256, 0, stream>>>(ei, gcur, parts, x, p0);

    // --- per-bucket sort (+ dinv, + p0 scaling) ---
    bsort_kernel<<<KB, 256, 0, stream>>>(parts, gcur, beg, end, dinv, p0);

    // --- FUSED layer-1 aggregation + transform -> fp16 p1 ---
    agg3trans_kernel<<<NV / 256, 256, 0, stream>>>(beg, end, parts, p0, dinv, W1, b1, p1h);

    // --- Layer 2 aggregation (fp16 gather, fp32 accumulate, fp16 out) ---
    agg64_kernel<<<NV * 64 / 256, 256, 0, stream>>>(beg, end, parts, p1h, q1h);

    // --- Fused layer-2 transform + partial pool (4x4 register-tiled GEMM) ---
    trans2pool_kernel<<<NWAVES / 4, 256, 0, stream>>>((const __half*)q1h, dinv, b2, W2, partials);

    // --- Head ---
    pool_finish_kernel<<<BB, 256, 0, stream>>>(partials, Wh, bh, out);
}